// Round 2
// baseline (5141.507 us; speedup 1.0000x reference)
//
#include <hip/hip_runtime.h>
#include <hip/hip_bf16.h>

#define Bq 256
#define Nn 256
#define Dd 256
#define Uu 256

using bf16 = __hip_bfloat16;

__device__ __forceinline__ float b2f(bf16 v) { return __bfloat162float(v); }
__device__ __forceinline__ float sigf(float x) { return 1.0f / (1.0f + __expf(-x)); }
__device__ __forceinline__ float tanh_(float x) { return 2.0f / (1.0f + __expf(-2.0f * x)) - 1.0f; }

// ---- cast recurrent weights fp32 -> bf16 (halves scan streaming bytes) ----
__global__ __launch_bounds__(256) void cast_weights(
    const float* __restrict__ wiou, const float* __restrict__ wf,
    bf16* __restrict__ wiou_b, bf16* __restrict__ wf_b) {
  int i = blockIdx.x * 256 + threadIdx.x;
  if (i < Uu * 3 * Uu) wiou_b[i] = __float2bfloat16(wiou[i]);
  if (i < Uu * Uu)     wf_b[i]   = __float2bfloat16(wf[i]);
}

// ---- phase 1: fiou_xb = inputs @ x_fiou + bias  (65536 x 1024, K=256) ----
// block: 256 threads, 16 rows x 1024 cols per block; fp32 VALU; bf16 output
__global__ __launch_bounds__(256) void xproj(
    const float* __restrict__ x, const float* __restrict__ w,
    const float* __restrict__ bias, bf16* __restrict__ out) {
  __shared__ float xs[Dd][16];  // transposed input tile: xs[k][r]
  const int tid = threadIdx.x;
  const int row0 = blockIdx.x * 16;

  // load 16x256 input rows into LDS (transposed), coalesced over k
  for (int i = 0; i < 16; ++i) {
    int idx = i * 256 + tid;
    int r = idx >> 8, k = idx & 255;
    xs[k][r] = x[(size_t)(row0 + r) * Dd + k];
  }
  __syncthreads();

  const int c0 = tid * 4;
  float4 bv = *(const float4*)(bias + c0);
  float acc[16][4];
#pragma unroll
  for (int r = 0; r < 16; ++r) {
    acc[r][0] = bv.x; acc[r][1] = bv.y; acc[r][2] = bv.z; acc[r][3] = bv.w;
  }

  for (int k = 0; k < Dd; ++k) {
    float4 wv = *(const float4*)(w + (size_t)k * 1024 + c0);
    const float4* xr = (const float4*)xs[k];
    float4 x0 = xr[0], x1 = xr[1], x2 = xr[2], x3 = xr[3];
    float xv[16] = {x0.x, x0.y, x0.z, x0.w, x1.x, x1.y, x1.z, x1.w,
                    x2.x, x2.y, x2.z, x2.w, x3.x, x3.y, x3.z, x3.w};
#pragma unroll
    for (int r = 0; r < 16; ++r) {
      acc[r][0] += xv[r] * wv.x;
      acc[r][1] += xv[r] * wv.y;
      acc[r][2] += xv[r] * wv.z;
      acc[r][3] += xv[r] * wv.w;
    }
  }

#pragma unroll
  for (int r = 0; r < 16; ++r) {
    union { ushort4 u4; bf16 b[4]; } pk;
    pk.b[0] = __float2bfloat16(acc[r][0]);
    pk.b[1] = __float2bfloat16(acc[r][1]);
    pk.b[2] = __float2bfloat16(acc[r][2]);
    pk.b[3] = __float2bfloat16(acc[r][3]);
    *(ushort4*)(&out[(size_t)(row0 + r) * 1024 + c0]) = pk.u4;
  }
}

// ---- phase 2: sequential tree scan. One block per batch, thread j = unit j.
// X serves as csh before a node is processed and hs after (post_orders is a
// permutation, so each node is processed exactly once; csh[tgt] is dead after
// its step and hs[tgt] = 0 + out). fiou layout per node: [f(0:256) i o u].
__global__ __launch_bounds__(256) void scan(
    const bf16* __restrict__ fiou, const int* __restrict__ parents,
    const int* __restrict__ post, const bf16* __restrict__ wiou_b,
    const bf16* __restrict__ wf_b, float* __restrict__ X,
    float* __restrict__ gcs) {
  const int b = blockIdx.x;
  const int j = threadIdx.x;
  __shared__ float hvec[Uu];
  __shared__ float ovec[Uu];
  const int base = b * Nn;

  for (int t = 0; t < Nn; ++t) {
    int po = post[base + t];
    bool om = (po >= 0);
    int tgt = om ? po : 0;
    int praw = parents[base + tgt];
    bool pm = (praw >= 0) && om;
    int par = (praw >= 0) ? praw : 0;

    size_t tb = (size_t)(base + tgt) * Uu;
    hvec[j] = X[tb + j];            // csh[tgt]
    float gc = gcs[tb + j];
    __syncthreads();  // hvec visible to all

    size_t fb = (size_t)(base + tgt) * (4 * Uu);
    float ai = b2f(fiou[fb + 1 * Uu + j]);
    float ao = b2f(fiou[fb + 2 * Uu + j]);
    float au = b2f(fiou[fb + 3 * Uu + j]);

    for (int k = 0; k < Uu; ++k) {
      float hk = hvec[k];
      ai += hk * b2f(wiou_b[k * (3 * Uu) + j]);
      ao += hk * b2f(wiou_b[k * (3 * Uu) + Uu + j]);
      au += hk * b2f(wiou_b[k * (3 * Uu) + 2 * Uu + j]);
    }

    float mem = sigf(ai) * tanh_(au) + gc;
    float out = sigf(ao) * tanh_(mem);
    ovec[j] = out;
    __syncthreads();  // ovec visible to all

    float af = b2f(fiou[(size_t)(base + par) * (4 * Uu) + j]);
    for (int k = 0; k < Uu; ++k) {
      af += ovec[k] * b2f(wf_b[k * Uu + j]);
    }
    float gated = sigf(af) * mem;

    if (om) X[tb + j] = out;        // hs[tgt] = out (overwrites dead csh)
    if (pm) {
      size_t pb = (size_t)(base + par) * Uu;
      X[pb + j] += out;             // csh[par] += out (par not yet processed)
      gcs[pb + j] += gated;
    }
    // next iter: only thread j touches column j in global mem (program-order
    // safe); LDS deps ordered by the two barriers per step.
  }
}

extern "C" void kernel_launch(void* const* d_in, const int* in_sizes, int n_in,
                              void* d_out, int out_size, void* d_ws, size_t ws_size,
                              hipStream_t stream) {
  const float* inputs = (const float*)d_in[0];
  const int* parents  = (const int*)d_in[1];
  const int* post     = (const int*)d_in[2];
  const float* xw     = (const float*)d_in[3];
  const float* hf     = (const float*)d_in[4];
  const float* hiou   = (const float*)d_in[5];
  const float* bias   = (const float*)d_in[6];
  float* X = (float*)d_out;  // csh-then-hs buffer

  // ws layout (192.5 MiB total, fits a 256 MiB workspace):
  //   [0, 128 MiB)              fiou_xb bf16   (B*N*4U)
  //   [128 MiB, 192 MiB)        gcs fp32       (B*N*U)
  //   [192 MiB, +512 KiB)       bf16 weights (wiou 384 KiB, wf 128 KiB)
  char* ws = (char*)d_ws;
  bf16* fiou   = (bf16*)ws;
  float* gcs   = (float*)(ws + (size_t)134217728);
  bf16* wiou_b = (bf16*)(ws + (size_t)201326592);
  bf16* wf_b   = (bf16*)(ws + (size_t)201326592 + 393216);

  hipMemsetAsync(X, 0, (size_t)Bq * Nn * Uu * sizeof(float), stream);
  hipMemsetAsync(gcs, 0, (size_t)Bq * Nn * Uu * sizeof(float), stream);

  cast_weights<<<768, 256, 0, stream>>>(hiou, hf, wiou_b, wf_b);
  xproj<<<(Bq * Nn) / 16, 256, 0, stream>>>(inputs, xw, bias, fiou);
  scan<<<Bq, 256, 0, stream>>>(fiou, parents, post, wiou_b, wf_b, X, gcs);
}